// Round 8
// baseline (210.155 us; speedup 1.0000x reference)
//
#include <hip/hip_runtime.h>

// out = atoms_x - segment_mean(atoms_x, graph_batch)[graph_batch]
// graph_batch SORTED. Fused, ONE WAVE PER BLOCK. All global access is
// DENSE/INTERLEAVED in the flat float layout (wave instr = 1KB, 16 lines,
// vs 64 lines for chunked per-thread ownership — the r7 limiter).
// Segment sums via per-element LDS atomics (ds_add_f32) into a per-block
// slot table; ids staged densely into LDS for O(1) per-element lookup.
// Ballot-stepped halo probes complete edge molecules.

typedef float f32x4 __attribute__((ext_vector_type(4)));

static constexpr int TPB   = 64;           // one wave
static constexpr int CPT   = 16;           // atoms per thread
static constexpr int CHUNK = TPB * CPT;    // 1024 atoms per block
static constexpr int F4PT  = CHUNK * 3 / 4 / TPB;  // 12 float4 per thread
static constexpr int I4PT  = CHUNK / 4 / TPB;      // 4 int4 per thread
static constexpr int SLOTS = 128;          // max id-span per chunk (exp ~27)

__global__ __launch_bounds__(TPB) void fused_center_kernel(
    const float* __restrict__ x, const int* __restrict__ gb,
    float* __restrict__ out, int n) {
  __shared__ alignas(16) int idbuf[CHUNK];
  __shared__ float sums[SLOTS * 4];  // {sx, sy, sz, cnt} per slot

  const int lane = threadIdx.x;
  const long long cs = (long long)blockIdx.x * CHUNK;
  const long long ce = (cs + CHUNK < (long long)n) ? cs + CHUNK : (long long)n;
  const int fid = gb[cs];
  const int lid = gb[ce - 1];
  const int span = lid - fid + 1;

  if (span > SLOTS) {
    // Pathological id-sparsity; block-uniform branch, never hot, correct.
    if (lane == 0) {
      long long i = cs;
      while (i < ce) {
        int id = gb[i];
        long long rs = i; while (rs > 0 && gb[rs - 1] == id) --rs;
        long long re = i; while (re < n && gb[re] == id) ++re;
        float sx = 0.f, sy = 0.f, sz = 0.f;
        for (long long k = rs; k < re; ++k) {
          sx += x[k * 3 + 0]; sy += x[k * 3 + 1]; sz += x[k * 3 + 2];
        }
        float inv = 1.f / (float)(re - rs);
        float mx = sx * inv, my = sy * inv, mz = sz * inv;
        long long we = (re < ce) ? re : ce;
        for (long long k = i; k < we; ++k) {
          out[k * 3 + 0] = x[k * 3 + 0] - mx;
          out[k * 3 + 1] = x[k * 3 + 1] - my;
          out[k * 3 + 2] = x[k * 3 + 2] - mz;
        }
        i = we;
      }
    }
    return;
  }

  const int na  = (int)(ce - cs);    // atoms in this block
  const int nf  = na * 3;            // flat floats
  const int nf4 = nf / 4;            // full float4s (remainder handled scalar)
  const int ni4 = na / 4;
  const int nir = na - ni4 * 4;

  // ---- dense flat loads of x into registers (1KB/instr, 16 lines) ----
  f32x4 xr[F4PT];
  const f32x4* xv = reinterpret_cast<const f32x4*>(x + cs * 3);
#pragma unroll
  for (int j = 0; j < F4PT; ++j) {
    int i4 = j * TPB + lane;
    xr[j] = (i4 < nf4) ? xv[i4] : (f32x4){0.f, 0.f, 0.f, 0.f};
  }

  // ---- dense id loads -> LDS (for O(1) per-element lookup) ----
  const int4* gv = reinterpret_cast<const int4*>(gb + cs);
#pragma unroll
  for (int j = 0; j < I4PT; ++j) {
    int i4 = j * TPB + lane;
    if (i4 < ni4)
      reinterpret_cast<int4*>(idbuf)[i4] = gv[i4];
  }
  if (lane < nir) idbuf[ni4 * 4 + lane] = gb[cs + ni4 * 4 + lane];

  // zero the slot table
  for (int i = lane; i < span * 4; i += TPB) sums[i] = 0.f;
  __syncthreads();  // single wave: cheap

  // ---- segment sum: per-element LDS atomics (flat indexing) ----
#pragma unroll
  for (int j = 0; j < F4PT; ++j) {
    int i4 = j * TPB + lane;
    if (i4 < nf4) {
      int e = i4 * 4;
      int atom = (int)(((unsigned)e * 0xAAABu) >> 17);  // e/3 (e < 3072)
      int comp = e - atom * 3;
#pragma unroll
      for (int c = 0; c < 4; ++c) {
        int s = (idbuf[atom] - fid) * 4;
        atomicAdd(&sums[s + comp], xr[j][c]);
        if (comp == 0) atomicAdd(&sums[s + 3], 1.f);
        if (++comp == 3) { comp = 0; ++atom; }
      }
    }
  }
  // scalar remainder elements (nf % 4 != 0 only possible on the tail block)
  for (int e = nf4 * 4 + lane; e < nf; e += TPB) {
    int atom = (int)(((unsigned)e * 0xAAABu) >> 17);
    int comp = e - atom * 3;
    int s = (idbuf[atom] - fid) * 4;
    atomicAdd(&sums[s + comp], x[cs * 3 + e]);
    if (comp == 0) atomicAdd(&sums[s + 3], 1.f);
  }

  // ---- halos: 64-lane ballot-stepped probes ----
  if (cs > 0) {
    float hx = 0.f, hy = 0.f, hz = 0.f, hc = 0.f;
    long long off = 1 + lane;
    for (;;) {
      long long i = cs - off;
      bool m = (i >= 0) && (gb[i] == fid);
      if (m) {
        hx += x[i * 3 + 0]; hy += x[i * 3 + 1]; hz += x[i * 3 + 2]; hc += 1.f;
      }
      if (__popcll(__ballot(m)) < TPB) break;
      off += TPB;
    }
#pragma unroll
    for (int d = 1; d < 64; d <<= 1) {
      hx += __shfl_xor(hx, d); hy += __shfl_xor(hy, d);
      hz += __shfl_xor(hz, d); hc += __shfl_xor(hc, d);
    }
    if (lane == 0 && hc > 0.f) {
      atomicAdd(&sums[0], hx); atomicAdd(&sums[1], hy);
      atomicAdd(&sums[2], hz); atomicAdd(&sums[3], hc);
    }
  }
  if (ce < (long long)n) {
    float hx = 0.f, hy = 0.f, hz = 0.f, hc = 0.f;
    long long off = (long long)lane;
    for (;;) {
      long long i = ce + off;
      bool m = (i < (long long)n) && (gb[i] == lid);
      if (m) {
        hx += x[i * 3 + 0]; hy += x[i * 3 + 1]; hz += x[i * 3 + 2]; hc += 1.f;
      }
      if (__popcll(__ballot(m)) < TPB) break;
      off += TPB;
    }
#pragma unroll
    for (int d = 1; d < 64; d <<= 1) {
      hx += __shfl_xor(hx, d); hy += __shfl_xor(hy, d);
      hz += __shfl_xor(hz, d); hc += __shfl_xor(hc, d);
    }
    if (lane == 0 && hc > 0.f) {
      int s = (lid - fid) * 4;
      atomicAdd(&sums[s + 0], hx); atomicAdd(&sums[s + 1], hy);
      atomicAdd(&sums[s + 2], hz); atomicAdd(&sums[s + 3], hc);
    }
  }
  __syncthreads();

  // ---- sums -> means ----
  for (int s = lane; s < span; s += TPB) {
    float c = sums[s * 4 + 3];
    if (c > 0.f) {
      float inv = 1.f / c;
      sums[s * 4 + 0] *= inv; sums[s * 4 + 1] *= inv; sums[s * 4 + 2] *= inv;
    }
  }
  __syncthreads();

  // ---- subtract + dense flat stores (1KB/instr, 16 lines) ----
  f32x4* ov = reinterpret_cast<f32x4*>(out + cs * 3);
#pragma unroll
  for (int j = 0; j < F4PT; ++j) {
    int i4 = j * TPB + lane;
    if (i4 < nf4) {
      int e = i4 * 4;
      int atom = (int)(((unsigned)e * 0xAAABu) >> 17);
      int comp = e - atom * 3;
      f32x4 o;
#pragma unroll
      for (int c = 0; c < 4; ++c) {
        int s = (idbuf[atom] - fid) * 4;
        o[c] = xr[j][c] - sums[s + comp];
        if (++comp == 3) { comp = 0; ++atom; }
      }
      ov[i4] = o;
    }
  }
  for (int e = nf4 * 4 + lane; e < nf; e += TPB) {
    int atom = (int)(((unsigned)e * 0xAAABu) >> 17);
    int comp = e - atom * 3;
    int s = (idbuf[atom] - fid) * 4;
    out[cs * 3 + e] = x[cs * 3 + e] - sums[s + comp];
  }
}

extern "C" void kernel_launch(void* const* d_in, const int* in_sizes, int n_in,
                              void* d_out, int out_size, void* d_ws, size_t ws_size,
                              hipStream_t stream) {
  const float* x = (const float*)d_in[0];
  const int* gb = (const int*)d_in[1];
  float* out = (float*)d_out;
  const int n = in_sizes[0] / 3;  // atoms

  int blocks = (int)(((long long)n + CHUNK - 1) / CHUNK);
  fused_center_kernel<<<blocks, TPB, 0, stream>>>(x, gb, out, n);
}

// Round 9
// 53.218 us; speedup vs baseline: 3.9490x; 3.9490x over previous
//
#include <hip/hip_runtime.h>

// out = atoms_x - segment_mean(atoms_x, graph_batch)[graph_batch]
// graph_batch SORTED. Fused single pass. 4 waves/block, but waves are FULLY
// INDEPENDENT (own 1024-atom chunk, own private LDS slot table, NO
// __syncthreads): removes the ~16-workgroup/CU residency cap that limited
// 1-wave blocks (r7, occ 35%) without reintroducing block lockstep (r4).
// Wave-internal LDS ordering via s_waitcnt lgkmcnt(0) (single PC per wave).
// Per-thread run accumulation + ballot-stepped halo probes (r7 reduction).

static constexpr int WAVE   = 64;
static constexpr int WPB    = 4;                 // waves per block
static constexpr int TPB    = WAVE * WPB;        // 256 threads
static constexpr int CPT    = 16;                // atoms per thread
static constexpr int WCHUNK = WAVE * CPT;        // 1024 atoms per wave
static constexpr int BCHUNK = WCHUNK * WPB;      // 4096 atoms per block
static constexpr int SLOTS  = 128;               // id-span per wave (exp ~27)

#define LDS_FENCE() asm volatile("s_waitcnt lgkmcnt(0)" ::: "memory")

__global__ __launch_bounds__(TPB) void fused_center_kernel(
    const float* __restrict__ x, const int* __restrict__ gb,
    float* __restrict__ out, int n) {
  __shared__ float sums_all[WPB][SLOTS * 4];  // private per-wave tables

  const int w = threadIdx.x >> 6;
  const int lane = threadIdx.x & 63;
  float* sums = sums_all[w];

  const long long cs = (long long)blockIdx.x * BCHUNK + (long long)w * WCHUNK;
  if (cs >= (long long)n) return;  // idle wave; no barriers anywhere -> safe
  const long long ce = (cs + WCHUNK < (long long)n) ? cs + WCHUNK : (long long)n;
  const int fid = gb[cs];
  const int lid = gb[ce - 1];
  const int span = lid - fid + 1;

  if (span > SLOTS) {
    // Pathological id-sparsity; wave-uniform branch, never hot, correct.
    if (lane == 0) {
      long long i = cs;
      while (i < ce) {
        int id = gb[i];
        long long rs = i; while (rs > 0 && gb[rs - 1] == id) --rs;
        long long re = i; while (re < n && gb[re] == id) ++re;
        float sx = 0.f, sy = 0.f, sz = 0.f;
        for (long long k = rs; k < re; ++k) {
          sx += x[k * 3 + 0]; sy += x[k * 3 + 1]; sz += x[k * 3 + 2];
        }
        float inv = 1.f / (float)(re - rs);
        float mx = sx * inv, my = sy * inv, mz = sz * inv;
        long long we = (re < ce) ? re : ce;
        for (long long k = i; k < we; ++k) {
          out[k * 3 + 0] = x[k * 3 + 0] - mx;
          out[k * 3 + 1] = x[k * 3 + 1] - my;
          out[k * 3 + 2] = x[k * 3 + 2] - mz;
        }
        i = we;
      }
    }
    return;
  }

  const long long base = cs + (long long)lane * CPT;
  const bool full = (base + CPT <= ce);

  // ---- issue all global loads first (hide latency under LDS init) ----
  float f[CPT * 3];
  int ids[CPT];
  if (full) {
    const float4* xv = reinterpret_cast<const float4*>(x + base * 3);
#pragma unroll
    for (int j = 0; j < CPT * 3 / 4; ++j) {
      float4 v = xv[j];
      f[j * 4 + 0] = v.x; f[j * 4 + 1] = v.y;
      f[j * 4 + 2] = v.z; f[j * 4 + 3] = v.w;
    }
    const int4* gv = reinterpret_cast<const int4*>(gb + base);
#pragma unroll
    for (int j = 0; j < CPT / 4; ++j) {
      int4 g = gv[j];
      ids[j * 4 + 0] = g.x; ids[j * 4 + 1] = g.y;
      ids[j * 4 + 2] = g.z; ids[j * 4 + 3] = g.w;
    }
  }

  // zero this wave's slot table
  for (int i = lane; i < span * 4; i += WAVE) sums[i] = 0.f;
  LDS_FENCE();

  if (full) {
    // ---- per-thread run accumulation, flush at id boundaries ----
    int cur = ids[0];
    float sx = 0.f, sy = 0.f, sz = 0.f, sc = 0.f;
#pragma unroll
    for (int j = 0; j < CPT; ++j) {
      if (ids[j] != cur) {
        int s = (cur - fid) * 4;
        atomicAdd(&sums[s + 0], sx); atomicAdd(&sums[s + 1], sy);
        atomicAdd(&sums[s + 2], sz); atomicAdd(&sums[s + 3], sc);
        cur = ids[j]; sx = sy = sz = sc = 0.f;
      }
      sx += f[j * 3 + 0]; sy += f[j * 3 + 1]; sz += f[j * 3 + 2]; sc += 1.f;
    }
    {
      int s = (cur - fid) * 4;
      atomicAdd(&sums[s + 0], sx); atomicAdd(&sums[s + 1], sy);
      atomicAdd(&sums[s + 2], sz); atomicAdd(&sums[s + 3], sc);
    }
  } else if (base < ce) {
    for (long long i = base; i < ce; ++i) {
      int s = (gb[i] - fid) * 4;
      atomicAdd(&sums[s + 0], x[i * 3 + 0]);
      atomicAdd(&sums[s + 1], x[i * 3 + 1]);
      atomicAdd(&sums[s + 2], x[i * 3 + 2]);
      atomicAdd(&sums[s + 3], 1.f);
    }
  }

  // ---- halos: 64-lane ballot-stepped probes ----
  if (cs > 0) {
    float hx = 0.f, hy = 0.f, hz = 0.f, hc = 0.f;
    long long off = 1 + lane;
    for (;;) {
      long long i = cs - off;
      bool m = (i >= 0) && (gb[i] == fid);
      if (m) {
        hx += x[i * 3 + 0]; hy += x[i * 3 + 1]; hz += x[i * 3 + 2]; hc += 1.f;
      }
      if (__popcll(__ballot(m)) < WAVE) break;
      off += WAVE;
    }
#pragma unroll
    for (int d = 1; d < 64; d <<= 1) {
      hx += __shfl_xor(hx, d); hy += __shfl_xor(hy, d);
      hz += __shfl_xor(hz, d); hc += __shfl_xor(hc, d);
    }
    if (lane == 0 && hc > 0.f) {
      atomicAdd(&sums[0], hx); atomicAdd(&sums[1], hy);
      atomicAdd(&sums[2], hz); atomicAdd(&sums[3], hc);
    }
  }
  if (ce < (long long)n) {
    float hx = 0.f, hy = 0.f, hz = 0.f, hc = 0.f;
    long long off = (long long)lane;
    for (;;) {
      long long i = ce + off;
      bool m = (i < (long long)n) && (gb[i] == lid);
      if (m) {
        hx += x[i * 3 + 0]; hy += x[i * 3 + 1]; hz += x[i * 3 + 2]; hc += 1.f;
      }
      if (__popcll(__ballot(m)) < WAVE) break;
      off += WAVE;
    }
#pragma unroll
    for (int d = 1; d < 64; d <<= 1) {
      hx += __shfl_xor(hx, d); hy += __shfl_xor(hy, d);
      hz += __shfl_xor(hz, d); hc += __shfl_xor(hc, d);
    }
    if (lane == 0 && hc > 0.f) {
      int s = (lid - fid) * 4;
      atomicAdd(&sums[s + 0], hx); atomicAdd(&sums[s + 1], hy);
      atomicAdd(&sums[s + 2], hz); atomicAdd(&sums[s + 3], hc);
    }
  }
  LDS_FENCE();

  // ---- sums -> means (this wave's table only) ----
  for (int s = lane; s < span; s += WAVE) {
    float c = sums[s * 4 + 3];
    if (c > 0.f) {
      float inv = 1.f / c;
      sums[s * 4 + 0] *= inv; sums[s * 4 + 1] *= inv; sums[s * 4 + 2] *= inv;
    }
  }
  LDS_FENCE();

  // ---- subtract + regular float4 stores (L2 assembles full lines) ----
  if (full) {
#pragma unroll
    for (int j = 0; j < CPT; ++j) {
      int s = (ids[j] - fid) * 4;
      f[j * 3 + 0] -= sums[s + 0];
      f[j * 3 + 1] -= sums[s + 1];
      f[j * 3 + 2] -= sums[s + 2];
    }
    float4* ov = reinterpret_cast<float4*>(out + base * 3);
#pragma unroll
    for (int j = 0; j < CPT * 3 / 4; ++j)
      ov[j] = make_float4(f[j * 4 + 0], f[j * 4 + 1],
                          f[j * 4 + 2], f[j * 4 + 3]);
  } else if (base < ce) {
    for (long long i = base; i < ce; ++i) {
      int s = (gb[i] - fid) * 4;
      out[i * 3 + 0] = x[i * 3 + 0] - sums[s + 0];
      out[i * 3 + 1] = x[i * 3 + 1] - sums[s + 1];
      out[i * 3 + 2] = x[i * 3 + 2] - sums[s + 2];
    }
  }
}

extern "C" void kernel_launch(void* const* d_in, const int* in_sizes, int n_in,
                              void* d_out, int out_size, void* d_ws, size_t ws_size,
                              hipStream_t stream) {
  const float* x = (const float*)d_in[0];
  const int* gb = (const int*)d_in[1];
  float* out = (float*)d_out;
  const int n = in_sizes[0] / 3;  // atoms

  int blocks = (int)(((long long)n + BCHUNK - 1) / BCHUNK);
  fused_center_kernel<<<blocks, TPB, 0, stream>>>(x, gb, out, n);
}